// Round 11
// baseline (1271.189 us; speedup 1.0000x reference)
//
#include <hip/hip_runtime.h>
#include <math.h>

// ---------------------------------------------------------------------------
// HAG-MoE forward. fp32 for all small ops; bf16 MFMA for the two big FFN
// GEMMs. Algebraic rewrites vs reference:
//  1) scores = (X@Wq)·a == X·(Wq@a): u = Wq@a_b, never materialize q.
//  2) h_moe = sum_ge w·(gelu(...)@W2) == (w*mid)@W2: fold router weight into
//     mid in FFN1's epilogue; b2 handled as weighted sum in k_final.
// Precision: PASSES template = 1|2|3 split-bf16 passes. r6 measured the
// full-split path at absmax 0.0039 vs thr 0.08125 (20x headroom) -> that
// error is baseline (ref-side), not FFN rounding. This round launches
// PASSES=1 (plain bf16, fp32 accum): predicted absmax 0.004-0.008.
// Fallback if fail: relaunch with PASSES=2/3 (template arg only).
// WORKSPACE: 54,288,384 B (51.8 MB). r6 post-timing divergence was ws
// overflow (101.5 MB footprint) corrupting the harness's pristine input
// copies via the OOB tail of `part`; footprint halved (mid bf16-hi only,
// part bf16) to fit.
// Perf model (r6 post-mortem): inline fp32->bf16 B-conversion is ~960
// VALU cyc/block/K-step vs ~930 MFMA cyc (3-pass) -> VALU-bound at ~150 TF.
// PASSES=1 cuts MFMA 3x but conversion only 2x -> predicted ~700-850 us.
// Next lever: pre-convert W1/W2 to bf16 in ws (needs ws_size >= ~280 MB).
// ---------------------------------------------------------------------------

#define Bb 256
#define Ss 128
#define Hh 768
#define Ii 3072
#define GE 24

typedef __attribute__((ext_vector_type(8))) short bf16x8;   // 8 bf16 in 4 VGPRs
typedef __attribute__((ext_vector_type(4))) short bf16x4;   // 8 B
typedef __attribute__((ext_vector_type(4))) float f32x4;

__device__ __forceinline__ short f2bf(float x) {            // fp32 -> bf16 RNE
    unsigned u = __float_as_uint(x);
    u += 0x7fffu + ((u >> 16) & 1u);
    return (short)(u >> 16);
}
__device__ __forceinline__ float bf2f(short h) {
    return __uint_as_float(((unsigned)(unsigned short)h) << 16);
}

// ---------------- generic fp32 tiled GEMM: BM=128, BN=64, BK=32 -------------
// EPI: 0 = none, 1 = +bias[n]
template<bool TRANSB, int EPI>
__global__ __launch_bounds__(256) void gemm_k(
    const float* __restrict__ A, int lda,
    const float* __restrict__ B, int ldb,
    float* __restrict__ C, int ldc,
    int M, int N, int K,
    const float* __restrict__ bias)
{
    constexpr int BM = 128, BN = 64, BK = 32;
    const int bm = blockIdx.y * BM, bn = blockIdx.x * BN;

    __shared__ float As[BK][BM + 4];
    __shared__ float Bs[BK][BN + 4];

    const int t = threadIdx.x;
    const int tm = t >> 4, tn = t & 15;   // 16x16 thread grid, 8x4 micro-tile
    float acc[8][4] = {};

    for (int k0 = 0; k0 < K; k0 += BK) {
        #pragma unroll
        for (int f = t; f < 1024; f += 256) {
            const int row = f >> 3, kc = f & 7;
            const float4 v = *(const float4*)&A[(long)(bm + row) * lda + k0 + kc * 4];
            As[kc * 4 + 0][row] = v.x; As[kc * 4 + 1][row] = v.y;
            As[kc * 4 + 2][row] = v.z; As[kc * 4 + 3][row] = v.w;
        }
        if (!TRANSB) {
            #pragma unroll
            for (int f = t; f < 512; f += 256) {
                const int kk = f >> 4, nc = f & 15;
                *(float4*)&Bs[kk][nc * 4] =
                    *(const float4*)&B[(long)(k0 + kk) * ldb + bn + nc * 4];
            }
        } else {
            // physical B is [N][K]; logical Bs[k][n] = B[n][k]
            #pragma unroll
            for (int f = t; f < 512; f += 256) {
                const int n = f >> 3, kc = f & 7;
                const float4 v = *(const float4*)&B[(long)(bn + n) * ldb + k0 + kc * 4];
                Bs[kc * 4 + 0][n] = v.x; Bs[kc * 4 + 1][n] = v.y;
                Bs[kc * 4 + 2][n] = v.z; Bs[kc * 4 + 3][n] = v.w;
            }
        }
        __syncthreads();
        #pragma unroll
        for (int k = 0; k < BK; ++k) {
            float a0[8], b0[4];
            *(float4*)&a0[0] = *(const float4*)&As[k][tm * 8];
            *(float4*)&a0[4] = *(const float4*)&As[k][tm * 8 + 4];
            *(float4*)&b0[0] = *(const float4*)&Bs[k][tn * 4];
            #pragma unroll
            for (int i = 0; i < 8; ++i)
                #pragma unroll
                for (int j = 0; j < 4; ++j)
                    acc[i][j] = fmaf(a0[i], b0[j], acc[i][j]);
        }
        __syncthreads();
    }

    #pragma unroll
    for (int i = 0; i < 8; ++i) {
        const int m = bm + tm * 8 + i;
        #pragma unroll
        for (int j = 0; j < 4; ++j) {
            const int n = bn + tn * 4 + j;
            float v = acc[i][j];
            if constexpr (EPI >= 1) v += bias[n];
            C[(long)m * ldc + n] = v;
        }
    }
}

// ------ MFMA bf16 GEMM: BM=MB (128|256), BN=64, BK=32, 4 waves -------------
// A: bf16 hi (and lo iff PASSES==3), row-major [m][k], elem off z*aZ+m*lda+k.
// B: fp32 [k][n], elem off z*bZ + k*ldb + n, converted to bf16 (hi, plus lo
//    iff PASSES>=2) inline, stored k-major in LDS.
// Out elem off: z*cZ + m*ldc + n.
// PASSES: 1 = Ah·Bh;  2 = Ah·Bh + Ah·Bl;  3 = + Al·Bh.
// EPI: 0 = fp32 out; 1 = bf16 out; 2 = gelu(v+bias[z*biasZ+n])*rowscale ->
//      bf16 out.
template<int MB, int EPI, int PASSES>
__global__ __launch_bounds__(256) void mfma_gemm(
    const short* __restrict__ Ahi, const short* __restrict__ Alo,
    long lda, long aZ,
    const float* __restrict__ B, int ldb, long bZ,
    float* __restrict__ Cf, short* __restrict__ Chi,
    long ldc, long cZ, int K,
    const float* __restrict__ bias, long biasZ,
    const float* __restrict__ rowscale, int nZ)
{
    static_assert(MB == 128 || MB == 256, "");
    static_assert(PASSES >= 1 && PASSES <= 3, "");
    constexpr int AP = (PASSES == 3) ? 2 : 1;   // A planes in LDS
    constexpr int BP = (PASSES >= 2) ? 2 : 1;   // B planes in LDS
    constexpr int BK = 32;
    constexpr int WROWS = MB / 4;               // rows per wave
    constexpr int MF = MB / 64;                 // 16-row m-fragments per wave
    const int z = blockIdx.z;
    const int bm = blockIdx.y * MB;
    const int bn = blockIdx.x * 64;
    const int t = threadIdx.x;
    const int wv = t >> 6, l = t & 63;
    const int lr = l & 15, lq = l >> 4;         // frag row/col, k-quad

    // rows padded to 40 bf16 (80 B): bank step 20 -> 2-way on b128 reads (free)
    __shared__ short As[AP][MB][40];            // [hi(/lo)][m][k]
    __shared__ short Bs[BP][64][40];            // [hi(/lo)][n][k]

    f32x4 acc[MF][4] = {};

    const int kp = t >> 4, nc = t & 15;         // B staging coords

    for (int k0 = 0; k0 < K; k0 += BK) {
        // ---- stage A: MB rows x 32 k, bf16x8 chunks
        #pragma unroll
        for (int f = t; f < MB * 4; f += 256) {
            const int m = f >> 2, seg = f & 3;
            const long ga = (long)z * aZ + (long)(bm + m) * lda + k0 + seg * 8;
            *(bf16x8*)&As[0][m][seg * 8] = *(const bf16x8*)&Ahi[ga];
            if constexpr (PASSES == 3)
                *(bf16x8*)&As[1][m][seg * 8] = *(const bf16x8*)&Alo[ga];
        }
        // ---- stage B: 2 k-rows x 4 n per thread, fp32 -> bf16, transpose
        {
            const float* Bz = B + (long)z * bZ + (long)(k0 + 2 * kp) * ldb + bn + nc * 4;
            const float4 q0 = *(const float4*)&Bz[0];
            const float4 q1 = *(const float4*)&Bz[ldb];
            float va[4], vb[4];
            va[0] = q0.x; va[1] = q0.y; va[2] = q0.z; va[3] = q0.w;
            vb[0] = q1.x; vb[1] = q1.y; vb[2] = q1.z; vb[3] = q1.w;
            #pragma unroll
            for (int j = 0; j < 4; ++j) {
                const int n = nc * 4 + j;
                const short h0 = f2bf(va[j]), h1 = f2bf(vb[j]);
                *(unsigned*)&Bs[0][n][2 * kp] =
                    (unsigned)(unsigned short)h0 | ((unsigned)(unsigned short)h1 << 16);
                if constexpr (PASSES >= 2) {
                    const short l0 = f2bf(va[j] - bf2f(h0));
                    const short l1 = f2bf(vb[j] - bf2f(h1));
                    *(unsigned*)&Bs[1][n][2 * kp] =
                        (unsigned)(unsigned short)l0 | ((unsigned)(unsigned short)l1 << 16);
                }
            }
        }
        __syncthreads();
        // ---- fragments + multi-pass MFMA
        bf16x8 af[AP][MF], bg[BP][4];
        #pragma unroll
        for (int mf = 0; mf < MF; ++mf) {
            af[0][mf] = *(const bf16x8*)&As[0][wv * WROWS + mf * 16 + lr][8 * lq];
            if constexpr (PASSES == 3)
                af[1][mf] = *(const bf16x8*)&As[1][wv * WROWS + mf * 16 + lr][8 * lq];
        }
        #pragma unroll
        for (int nf = 0; nf < 4; ++nf) {
            bg[0][nf] = *(const bf16x8*)&Bs[0][nf * 16 + lr][8 * lq];
            if constexpr (PASSES >= 2)
                bg[1][nf] = *(const bf16x8*)&Bs[1][nf * 16 + lr][8 * lq];
        }
        #pragma unroll
        for (int mf = 0; mf < MF; ++mf)
            #pragma unroll
            for (int nf = 0; nf < 4; ++nf) {
                acc[mf][nf] = __builtin_amdgcn_mfma_f32_16x16x32_bf16(
                    af[0][mf], bg[0][nf], acc[mf][nf], 0, 0, 0);
                if constexpr (PASSES >= 2)
                    acc[mf][nf] = __builtin_amdgcn_mfma_f32_16x16x32_bf16(
                        af[0][mf], bg[1][nf], acc[mf][nf], 0, 0, 0);
                if constexpr (PASSES == 3)
                    acc[mf][nf] = __builtin_amdgcn_mfma_f32_16x16x32_bf16(
                        af[1][mf], bg[0][nf], acc[mf][nf], 0, 0, 0);
            }
        __syncthreads();
    }

    // ---- epilogue: C/D layout col=lane&15, row=(lane>>4)*4+reg [m89]
    #pragma unroll
    for (int mf = 0; mf < MF; ++mf)
        #pragma unroll
        for (int nf = 0; nf < 4; ++nf)
            #pragma unroll
            for (int r = 0; r < 4; ++r) {
                const int m = bm + wv * WROWS + mf * 16 + 4 * lq + r;
                const int n = bn + nf * 16 + lr;
                float v = acc[mf][nf][r];
                const long ci = (long)z * cZ + (long)m * ldc + n;
                if constexpr (EPI == 2) {
                    v += bias[(long)z * biasZ + n];
                    v = 0.5f * v * (1.0f + erff(v * 0.70710678118654752440f));
                    v *= rowscale[m * nZ + z];
                    Chi[ci] = f2bf(v);
                } else if constexpr (EPI == 1) {
                    Chi[ci] = f2bf(v);
                } else {
                    Cf[ci] = v;
                }
            }
}

// ---------------- split fp32 vector into bf16 hi/lo (4 elems/thread) -------
// n must be divisible by 4; all pointers float4/8B-aligned.
// (lo kept for the PASSES=3 fallback path; cost is negligible.)
__global__ __launch_bounds__(256) void k_splitA(
    const float* __restrict__ x, short* __restrict__ hi, short* __restrict__ lo, int n)
{
    const int i4 = blockIdx.x * 256 + threadIdx.x;          // index in float4 units
    if (i4 * 4 < n) {
        const float4 v = ((const float4*)x)[i4];
        float vv[4] = {v.x, v.y, v.z, v.w};
        bf16x4 h4, l4;
        #pragma unroll
        for (int j = 0; j < 4; ++j) {
            const short h = f2bf(vv[j]);
            h4[j] = h;
            l4[j] = f2bf(vv[j] - bf2f(h));
        }
        *(bf16x4*)&hi[i4 * 4] = h4;
        *(bf16x4*)&lo[i4 * 4] = l4;
    }
}

// ------------- scores + softmax + pooling, one block per batch row ----------
// float4-vectorized X reads (G13): 192 float4 columns per 768-wide row.
__global__ __launch_bounds__(256) void k_pool(
    const float* __restrict__ X, const int* __restrict__ mask,
    const float* __restrict__ u, float* __restrict__ hop)
{
    const int b = blockIdx.x, t = threadIdx.x;
    const int lane = t & 63, wv = t >> 6;
    __shared__ float4 su4[192];
    __shared__ float sc[Ss];
    __shared__ float red[256];
    const float4* xb4 = (const float4*)(X + (long)b * Ss * Hh);  // [128][192]

    if (t < 192) su4[t] = ((const float4*)(u + (long)b * Hh))[t];
    __syncthreads();

    // each wave: 32 score rows; dot(x[b,s,:], u)/sqrt(H), 3 float4 per lane
    for (int s = wv * 32; s < wv * 32 + 32; ++s) {
        float a = 0.f;
        #pragma unroll
        for (int k = 0; k < 3; ++k) {
            const int i = lane + 64 * k;
            const float4 x4 = xb4[(long)s * 192 + i];
            const float4 u4 = su4[i];
            a = fmaf(x4.x, u4.x, a); a = fmaf(x4.y, u4.y, a);
            a = fmaf(x4.z, u4.z, a); a = fmaf(x4.w, u4.w, a);
        }
        #pragma unroll
        for (int off = 32; off; off >>= 1) a += __shfl_down(a, off);
        if (lane == 0)
            sc[s] = (mask[b * Ss + s] == 0) ? -3.4028234663852886e38f
                                            : a * 0.036084391824351615f; // 1/sqrt(768)
    }
    __syncthreads();

    // softmax over S=128
    red[t] = (t < Ss) ? sc[t] : -3.4028234663852886e38f;
    __syncthreads();
    for (int off = 128; off >= 1; off >>= 1) {
        if (t < off) red[t] = fmaxf(red[t], red[t + off]);
        __syncthreads();
    }
    const float mx = red[0];
    __syncthreads();
    const float e = (t < Ss) ? expf(sc[t] - mx) : 0.f;
    red[t] = e;
    __syncthreads();
    for (int off = 128; off >= 1; off >>= 1) {
        if (t < off) red[t] += red[t + off];
        __syncthreads();
    }
    const float inv = 1.f / red[0];
    if (t < Ss) sc[t] = e * inv;
    __syncthreads();

    // pooled h_opinion: lane t<192 owns one float4 column
    if (t < 192) {
        float4 acc = make_float4(0.f, 0.f, 0.f, 0.f);
        for (int s = 0; s < Ss; ++s) {
            const float w = sc[s];
            const float4 x4 = xb4[(long)s * 192 + t];
            acc.x = fmaf(w, x4.x, acc.x); acc.y = fmaf(w, x4.y, acc.y);
            acc.z = fmaf(w, x4.z, acc.z); acc.w = fmaf(w, x4.w, acc.w);
        }
        ((float4*)(hop + (long)b * Hh))[t] = acc;
    }
}

// ---------------- LayerNorm over concat(h_opinion, h_aspect) ---------------
__global__ __launch_bounds__(256) void k_ln(
    const float* __restrict__ hop, const float* __restrict__ asp,
    const float* __restrict__ g, const float* __restrict__ bta,
    float* __restrict__ catn)
{
    const int b = blockIdx.x, t = threadIdx.x;
    __shared__ float c[2 * Hh];
    __shared__ float red[256];
    for (int i = t; i < Hh; i += 256) { c[i] = hop[b * Hh + i]; c[Hh + i] = asp[b * Hh + i]; }
    __syncthreads();
    float s = 0.f;
    for (int i = t; i < 2 * Hh; i += 256) s += c[i];
    red[t] = s; __syncthreads();
    for (int off = 128; off >= 1; off >>= 1) { if (t < off) red[t] += red[t + off]; __syncthreads(); }
    const float mu = red[0] / (2.f * Hh);
    __syncthreads();
    float s2 = 0.f;
    for (int i = t; i < 2 * Hh; i += 256) { const float d = c[i] - mu; s2 = fmaf(d, d, s2); }
    red[t] = s2; __syncthreads();
    for (int off = 128; off >= 1; off >>= 1) { if (t < off) red[t] += red[t + off]; __syncthreads(); }
    const float rstd = rsqrtf(red[0] / (2.f * Hh) + 1e-5f);
    for (int i = t; i < 2 * Hh; i += 256)
        catn[(long)b * 2 * Hh + i] = fmaf((c[i] - mu) * rstd, g[i], bta[i]);
}

// ---------------- cat2 = [h_fused, h_aspect] -------------------------------
__global__ __launch_bounds__(256) void k_cat2(
    const float* __restrict__ hf, const float* __restrict__ asp,
    float* __restrict__ cat2)
{
    const long i = (long)blockIdx.x * 256 + threadIdx.x;   // < B*2H
    const int b = (int)(i / (2 * Hh)), r = (int)(i % (2 * Hh));
    cat2[i] = (r < Hh) ? hf[b * Hh + r] : asp[b * Hh + (r - Hh)];
}

// ---------------- hierarchical router: w[b,ge] = p_group*p_expert ----------
__global__ __launch_bounds__(256) void k_router(
    const float* __restrict__ hf, const float* __restrict__ hc,
    const float* __restrict__ Wgr, const float* __restrict__ bgr,
    const float* __restrict__ Wer, const float* __restrict__ ber,
    float* __restrict__ w)
{
    const int b = blockIdx.x, t = threadIdx.x;
    const int lane = t & 63, wv = t >> 6;
    __shared__ float logits[27];  // [0..2]=group, [3..26]=expert g*8+e
    __shared__ float pg[3], pe[24];

    for (int o = wv; o < 27; o += 4) {
        float a = 0.f;
        if (o < 3) {
            #pragma unroll
            for (int k = 0; k < 12; ++k) {
                const int h = lane + 64 * k;
                a = fmaf(hf[b * Hh + h], Wgr[h * 3 + o], a);
            }
        } else {
            const int ge = o - 3, g = ge >> 3, e = ge & 7;
            #pragma unroll
            for (int k = 0; k < 12; ++k) {
                const int h = lane + 64 * k;
                a = fmaf(hc[b * Hh + h], Wer[((long)g * Hh + h) * 8 + e], a);
            }
        }
        #pragma unroll
        for (int off = 32; off; off >>= 1) a += __shfl_down(a, off);
        if (lane == 0) logits[o] = a + ((o < 3) ? bgr[o] : ber[o - 3]);
    }
    __syncthreads();
    if (t == 0) {
        const float m = fmaxf(fmaxf(logits[0], logits[1]), logits[2]);
        const float e0 = expf(logits[0] - m), e1 = expf(logits[1] - m), e2 = expf(logits[2] - m);
        const float inv = 1.f / (e0 + e1 + e2);
        pg[0] = e0 * inv; pg[1] = e1 * inv; pg[2] = e2 * inv;
    }
    if (t < 3) {
        const int g = t;
        float m = -3.4028234663852886e38f;
        for (int e = 0; e < 8; ++e) m = fmaxf(m, logits[3 + g * 8 + e]);
        float sum = 0.f, ex[8];
        for (int e = 0; e < 8; ++e) { ex[e] = expf(logits[3 + g * 8 + e] - m); sum += ex[e]; }
        const float inv = 1.f / sum;
        for (int e = 0; e < 8; ++e) pe[g * 8 + e] = ex[e] * inv;
    }
    __syncthreads();
    if (t < 24) w[b * GE + t] = pg[t >> 3] * pe[t];
}

// ---------------- final: residual + sum partials (bf16) + b2 term ----------
__global__ __launch_bounds__(256) void k_final(
    const float* __restrict__ hf, const short* __restrict__ part,
    const float* __restrict__ w, const float* __restrict__ b2,
    float* __restrict__ out)
{
    const long i = (long)blockIdx.x * 256 + threadIdx.x;   // < B*H
    const int b = (int)(i / Hh), h = (int)(i % Hh);
    float a = hf[i];
    #pragma unroll
    for (int z = 0; z < GE; ++z) a += bf2f(part[(long)z * (Bb * Hh) + i]);
    float wb = 0.f;
    #pragma unroll
    for (int z = 0; z < GE; ++z) wb = fmaf(w[b * GE + z], b2[z * Hh + h], wb);
    out[i] = a + wb;
}

// ---------------------------------------------------------------------------
extern "C" void kernel_launch(void* const* d_in, const int* in_sizes, int n_in,
                              void* d_out, int out_size, void* d_ws, size_t ws_size,
                              hipStream_t stream)
{
    const float* X   = (const float*)d_in[0];   // [B,S,H]
    const int*   msk = (const int*)  d_in[1];   // [B,S]
    const float* asp = (const float*)d_in[2];   // [B,H]
    const float* Wq  = (const float*)d_in[3];   // [H,H]
    const float* lng = (const float*)d_in[4];
    const float* lnb = (const float*)d_in[5];
    const float* Wf  = (const float*)d_in[6];   // [2H,H]
    const float* bf  = (const float*)d_in[7];
    const float* Wgr = (const float*)d_in[8];   // [H,G]
    const float* bgr = (const float*)d_in[9];
    const float* Wc  = (const float*)d_in[10];  // [2H,H]
    const float* bc  = (const float*)d_in[11];
    const float* Wer = (const float*)d_in[12];  // [G,H,E]
    const float* ber = (const float*)d_in[13];  // [G,E]
    const float* W1  = (const float*)d_in[14];  // [G,E,H,I]
    const float* b1  = (const float*)d_in[15];  // [G,E,I]
    const float* W2  = (const float*)d_in[16];  // [G,E,I,H]
    const float* b2  = (const float*)d_in[17];  // [G,E,H]
    float* out = (float*)d_out;

    // ---- workspace layout (float offsets unless noted); total 51.8 MB ----
    float* ws     = (float*)d_ws;
    float* u      = ws;                    // B*H = 196608 floats
    float* hop    = ws + 196608;           // B*H
    float* catn   = ws + 393216;           // B*2H
    float* hfused = ws + 786432;           // B*H
    float* cat2   = ws + 983040;           // B*2H
    float* hcond  = ws + 1376256;          // B*H
    float* wbe    = ws + 1572864;          // B*24 = 6144
    short* Ahi    = (short*)(ws + 1579008);       // B*H shorts (393,216 B)
    short* Alo    = Ahi + 196608;                 // B*H shorts
    short* midhi  = Alo + 196608;                 // B*GE*I shorts (37.75 MB)
    short* part   = midhi + (long)Bb * GE * Ii;   // GE*B*H shorts (9.44 MB)
    // end byte offset: 54,288,384

    // G1: u[b,n] = sum_k asp[b,k] * Wq[n,k]   (u = Wq @ a_b)
    gemm_k<true, 0><<<dim3(12, 2), 256, 0, stream>>>(
        asp, Hh, Wq, Hh, u, Hh, Bb, Hh, Hh, nullptr);

    k_pool<<<Bb, 256, 0, stream>>>(X, msk, u, hop);
    k_ln<<<Bb, 256, 0, stream>>>(hop, asp, lng, lnb, catn);

    // G2: h_fused = catn @ Wf + bf
    gemm_k<false, 1><<<dim3(12, 2), 256, 0, stream>>>(
        catn, 2 * Hh, Wf, Hh, hfused, Hh, Bb, Hh, 2 * Hh, bf);

    k_splitA<<<192, 256, 0, stream>>>(hfused, Ahi, Alo, Bb * Hh);
    k_cat2<<<(Bb * 2 * Hh) / 256, 256, 0, stream>>>(hfused, asp, cat2);

    // G3: h_cond = cat2 @ Wc + bc
    gemm_k<false, 1><<<dim3(12, 2), 256, 0, stream>>>(
        cat2, 2 * Hh, Wc, Hh, hcond, Hh, Bb, Hh, 2 * Hh, bc);

    k_router<<<Bb, 256, 0, stream>>>(hfused, hcond, Wgr, bgr, Wer, ber, wbe);

    // G4 (FFN1, z=24): mid = gelu(h_fused@W1_z + b1_z)*w -> bf16 hi
    // PASSES=1 plain bf16 (r6 measured full-split absmax 0.0039 << 0.08125;
    // error is baseline-dominated, so 1-pass predicted ~0.004-0.008).
    // mid layout [m][z*I + n]: ldc = GE*I, cZ = I.
    // MB=256: weights read once; grid 48*24 = 1152 blocks (4.5/CU, balanced)
    mfma_gemm<256, 2, 1><<<dim3(Ii / 64, 1, GE), 256, 0, stream>>>(
        Ahi, Alo, Hh, 0,
        W1, Ii, (long)Hh * Ii,
        nullptr, midhi,
        (long)GE * Ii, Ii, Hh,
        b1, Ii, wbe, GE);

    // G5 (FFN2, z=24): part_z = mid_z @ W2_z  (PASSES=1; bf16 out)
    // MB=128: grid 576 blocks (2.25/CU) -> balance 3/2.25 = 1.33x over ideal.
    mfma_gemm<128, 1, 1><<<dim3(Hh / 64, 2, GE), 256, 0, stream>>>(
        midhi, nullptr, (long)GE * Ii, Ii,
        W2, Hh, (long)Ii * Hh,
        nullptr, part,
        Hh, (long)Bb * Hh, Ii,
        nullptr, 0, nullptr, 0);

    k_final<<<(Bb * Hh) / 256, 256, 0, stream>>>(hfused, part, wbe, b2, out);
}